// Round 3
// baseline (42.207 us; speedup 1.0000x reference)
//
#include <hip/hip_runtime.h>
#include <math.h>

#define NQ 12
#define NN 4096   // 2^12

__device__ __forceinline__ float2 cmul(float2 a, float2 b) {
    return make_float2(a.x * b.x - a.y * b.y, a.x * b.y + a.y * b.x);
}
__device__ __forceinline__ float2 cmadd(float2 a, float2 b, float2 acc) {
    acc.x = fmaf(a.x, b.x, fmaf(-a.y, b.y, acc.x));
    acc.y = fmaf(a.x, b.y, fmaf(a.y, b.x, acc.y));
    return acc;
}

// LDS address swizzle: XOR low-4 element bits with bits [7:4].
// Puts every b64 transpose access pattern at the 4-access/bank floor.
__device__ __forceinline__ int swz(int i) { return i ^ ((i >> 4) & 0xF); }

// Generic radix-2 butterfly on slot bit log2(D) with 2x2 complex matrix m.
template<int D>
__device__ __forceinline__ void stage(float2 (&v)[16],
                                      float2 m00, float2 m01,
                                      float2 m10, float2 m11) {
    #pragma unroll
    for (int s = 0; s < 16; ++s) {
        if (s & D) continue;
        float2 va = v[s], vb = v[s | D];
        float2 r0 = cmul(m00, va); r0 = cmadd(m01, vb, r0);
        float2 r1 = cmul(m10, va); r1 = cmadd(m11, vb, r1);
        v[s] = r0; v[s | D] = r1;
    }
}

// Process one row already resident in v[16] under mapping A; ends with the
// coalesced store of this row. Uses lds for the two transposes (3 barriers:
// the first also protects lds reuse against the previous row's reads).
__device__ __forceinline__ void process_row(float2 (&v)[16], float2* lds,
                                            const float2* Msh, float* out,
                                            size_t rowoff, int T) {
    // ---- phase 1: bits 0 (d=1), 1 (d=2), 10 (d=4), 11 (d=8) ----
    stage<1>(v, Msh[0],  Msh[1],  Msh[2],  Msh[3]);    // bit 0
    stage<2>(v, Msh[4],  Msh[5],  Msh[6],  Msh[7]);    // bit 1
    stage<4>(v, Msh[40], Msh[41], Msh[42], Msh[43]);   // bit 10
    stage<8>(v, Msh[44], Msh[45], Msh[46], Msh[47]);   // bit 11

    __syncthreads();  // previous row's lds reads are done before we overwrite
    // ---- transpose A -> B ----
    #pragma unroll
    for (int s = 0; s < 16; ++s) {
        int i = ((s >> 2) << 10) | (T << 2) | (s & 3);
        lds[swz(i)] = v[s];
    }
    __syncthreads();
    const int bB = ((T >> 6) << 10) | (((T >> 2) & 0xF) << 6) | (T & 3);
    #pragma unroll
    for (int s = 0; s < 16; ++s) v[s] = lds[swz(bB | (s << 2))];

    // ---- phase 2: bits 2,3,4,5 ----
    stage<1>(v, Msh[8],  Msh[9],  Msh[10], Msh[11]);   // bit 2
    stage<2>(v, Msh[12], Msh[13], Msh[14], Msh[15]);   // bit 3
    stage<4>(v, Msh[16], Msh[17], Msh[18], Msh[19]);   // bit 4
    stage<8>(v, Msh[20], Msh[21], Msh[22], Msh[23]);   // bit 5

    // ---- transpose B -> C (writes hit only this thread's own read addrs) ----
    #pragma unroll
    for (int s = 0; s < 16; ++s) lds[swz(bB | (s << 2))] = v[s];
    __syncthreads();
    const int bC = ((T >> 6) << 10) | (T & 63);
    #pragma unroll
    for (int s = 0; s < 16; ++s) v[s] = lds[swz(bC | (s << 6))];

    // ---- phase 3: bits 6,7,8,9 ----
    stage<1>(v, Msh[24], Msh[25], Msh[26], Msh[27]);   // bit 6
    stage<2>(v, Msh[28], Msh[29], Msh[30], Msh[31]);   // bit 7
    stage<4>(v, Msh[32], Msh[33], Msh[34], Msh[35]);   // bit 8
    stage<8>(v, Msh[36], Msh[37], Msh[38], Msh[39]);   // bit 9

    // ---- store (mapping C): per slot, 64 consecutive dwords per wave ----
    #pragma unroll
    for (int s = 0; s < 16; ++s) {
        int i = bC | (s << 6);
        out[rowoff + i]      = v[s].x;
        out[rowoff + NN + i] = v[s].y;
    }
}

// One block processes TWO batch rows; grid = B/2 = 1024 blocks so the whole
// grid is resident (no ramp generations). Row 1's global loads are issued
// into registers before row 0's compute so memory overlaps VALU work.
// Thread T holds 16 complex elements, mapping A: i = rhi<<10 | T<<2 | c.
__global__ __launch_bounds__(256) void sq_layer(const float* __restrict__ x,
                                                float* __restrict__ out,
                                                const float* __restrict__ alphas,
                                                const float* __restrict__ betas,
                                                const float* __restrict__ thetas,
                                                const float* __restrict__ phis) {
    __shared__ float2 lds[NN];   // 32 KB
    __shared__ float2 Msh[48];
    const int T = threadIdx.x;

    // ---- per-block setup: M_p for bit position p = 0..11 ----
    // M_p = diag(e^{i phi},1) * u * diag(e^{i theta},1) * u * diag(e^{i a}, e^{i b})
    // with u = (1/sqrt2)[[1,i],[i,1]], parameter index q = 11-p.
    if (T < NQ) {
        int p = T, q = NQ - 1 - p;
        float sa, ca, sb, cb, st, ct, sf, cf;
        sincosf(alphas[q], &sa, &ca);
        sincosf(betas[q],  &sb, &cb);
        sincosf(thetas[q], &st, &ct);
        sincosf(phis[q],   &sf, &cf);
        float2 A  = make_float2(ca, sa);
        float2 Bb = make_float2(cb, sb);
        float2 F  = make_float2(cf, sf);
        float2 Tm  = make_float2(0.5f * (ct - 1.0f), 0.5f * st);  // (T-1)/2
        float2 Tp  = make_float2(0.5f * (ct + 1.0f), 0.5f * st);  // (T+1)/2
        float2 iTp = make_float2(-Tp.y, Tp.x);                    // i*(T+1)/2
        Msh[p * 4 + 0] = cmul(cmul(F, Tm), A);
        Msh[p * 4 + 1] = cmul(cmul(F, iTp), Bb);
        Msh[p * 4 + 2] = cmul(iTp, A);
        Msh[p * 4 + 3] = cmul(make_float2(-Tm.x, -Tm.y), Bb);
    }

    const size_t off0 = (size_t)(blockIdx.x * 2) * (2 * NN);
    const size_t off1 = off0 + 2 * NN;

    // ---- load row 0 (mapping A), coalesced float4 ----
    float2 v[16];
    #pragma unroll
    for (int rhi = 0; rhi < 4; ++rhi) {
        int base = (rhi << 10) + (T << 2);
        float4 re4 = *reinterpret_cast<const float4*>(x + off0 + base);
        float4 im4 = *reinterpret_cast<const float4*>(x + off0 + NN + base);
        v[rhi * 4 + 0] = make_float2(re4.x, im4.x);
        v[rhi * 4 + 1] = make_float2(re4.y, im4.y);
        v[rhi * 4 + 2] = make_float2(re4.z, im4.z);
        v[rhi * 4 + 3] = make_float2(re4.w, im4.w);
    }
    // ---- prefetch row 1 into registers (latency hides under row-0 work) ----
    float4 pr0, pr1, pr2, pr3, pi0, pi1, pi2, pi3;
    {
        int base = (T << 2);
        pr0 = *reinterpret_cast<const float4*>(x + off1 + base);
        pi0 = *reinterpret_cast<const float4*>(x + off1 + NN + base);
        pr1 = *reinterpret_cast<const float4*>(x + off1 + 1024 + base);
        pi1 = *reinterpret_cast<const float4*>(x + off1 + NN + 1024 + base);
        pr2 = *reinterpret_cast<const float4*>(x + off1 + 2048 + base);
        pi2 = *reinterpret_cast<const float4*>(x + off1 + NN + 2048 + base);
        pr3 = *reinterpret_cast<const float4*>(x + off1 + 3072 + base);
        pi3 = *reinterpret_cast<const float4*>(x + off1 + NN + 3072 + base);
    }

    __syncthreads();  // Msh ready

    process_row(v, lds, Msh, out, off0, T);

    // ---- row 1: move prefetched data into v ----
    v[0]  = make_float2(pr0.x, pi0.x); v[1]  = make_float2(pr0.y, pi0.y);
    v[2]  = make_float2(pr0.z, pi0.z); v[3]  = make_float2(pr0.w, pi0.w);
    v[4]  = make_float2(pr1.x, pi1.x); v[5]  = make_float2(pr1.y, pi1.y);
    v[6]  = make_float2(pr1.z, pi1.z); v[7]  = make_float2(pr1.w, pi1.w);
    v[8]  = make_float2(pr2.x, pi2.x); v[9]  = make_float2(pr2.y, pi2.y);
    v[10] = make_float2(pr2.z, pi2.z); v[11] = make_float2(pr2.w, pi2.w);
    v[12] = make_float2(pr3.x, pi3.x); v[13] = make_float2(pr3.y, pi3.y);
    v[14] = make_float2(pr3.z, pi3.z); v[15] = make_float2(pr3.w, pi3.w);

    process_row(v, lds, Msh, out, off1, T);
}

extern "C" void kernel_launch(void* const* d_in, const int* in_sizes, int n_in,
                              void* d_out, int out_size, void* d_ws, size_t ws_size,
                              hipStream_t stream) {
    const float* x      = (const float*)d_in[0];
    const float* alphas = (const float*)d_in[1];
    const float* betas  = (const float*)d_in[2];
    const float* thetas = (const float*)d_in[3];
    const float* phis   = (const float*)d_in[4];
    float* out = (float*)d_out;

    const int B = in_sizes[0] / (2 * NN);  // 2048
    const int nblk = B / 2;                // 1024 — fully resident

    hipLaunchKernelGGL(sq_layer, dim3(nblk), dim3(256), 0, stream,
                       x, out, alphas, betas, thetas, phis);
}

// Round 4
// 33.719 us; speedup vs baseline: 1.2517x; 1.2517x over previous
//
#include <hip/hip_runtime.h>
#include <math.h>

#define NQ 12
#define NN 4096   // 2^12

typedef float f2 __attribute__((ext_vector_type(2)));  // (re, im) in a VGPR pair

__device__ __forceinline__ float2 cmulh(float2 a, float2 b) {
    return make_float2(a.x * b.x - a.y * b.y, a.x * b.y + a.y * b.x);
}

// ---- packed complex arithmetic: 2 x v_pk_fma_f32 per complex MAC ----
// m = [mr, mi] (SGPR pair, uniform), b = [br, bi], acc = [ar, ai].
// inst1: lo += mr*br        hi += mr*bi      (src0 broadcasts m.lo)
// inst2: lo += -mi*bi       hi += mi*br      (src0 broadcasts m.hi, swap b halves, neg lo)
__device__ __forceinline__ void cmac_pk(f2& acc, f2 m, f2 b) {
    asm("v_pk_fma_f32 %0, %1, %2, %0 op_sel:[0,0,0] op_sel_hi:[0,1,1]\n\t"
        "v_pk_fma_f32 %0, %1, %2, %0 op_sel:[1,1,0] op_sel_hi:[1,0,1] neg_lo:[1,0,0]"
        : "+v"(acc) : "s"(m), "v"(b));
}
__device__ __forceinline__ void cmul_pk(f2& r, f2 m, f2 b) {
    asm("v_pk_mul_f32 %0, %1, %2 op_sel:[0,0] op_sel_hi:[0,1]\n\t"
        "v_pk_fma_f32 %0, %1, %2, %0 op_sel:[1,1,0] op_sel_hi:[1,0,1] neg_lo:[1,0,0]"
        : "=&v"(r) : "s"(m), "v"(b));
}

// Radix-2 butterfly on slot bit log2(D) with 2x2 complex matrix (m00,m01;m10,m11).
template<int D>
__device__ __forceinline__ void stagepk(f2 (&v)[16], f2 m00, f2 m01, f2 m10, f2 m11) {
    #pragma unroll
    for (int s = 0; s < 16; ++s) {
        if (s & D) continue;
        f2 va = v[s], vb = v[s | D];
        f2 r0, r1;
        cmul_pk(r0, m00, va); cmac_pk(r0, m01, vb);
        cmul_pk(r1, m10, va); cmac_pk(r1, m11, vb);
        v[s] = r0; v[s | D] = r1;
    }
}

// d_ws: Mg[p*4 + {m00,m01,m10,m11}] for bit position p = 0..11.
// M_p = diag(e^{i phi},1) * u * diag(e^{i theta},1) * u * diag(e^{i a}, e^{i b}),
// u = (1/sqrt2)[[1,i],[i,1]], parameter index q = 11-p.
__global__ void setup_mats(const float* __restrict__ alphas,
                           const float* __restrict__ betas,
                           const float* __restrict__ thetas,
                           const float* __restrict__ phis,
                           float2* __restrict__ Mg) {
    int t = threadIdx.x;
    if (t < NQ) {
        int p = t, q = NQ - 1 - p;
        float sa, ca, sb, cb, st, ct, sf, cf;
        sincosf(alphas[q], &sa, &ca);
        sincosf(betas[q],  &sb, &cb);
        sincosf(thetas[q], &st, &ct);
        sincosf(phis[q],   &sf, &cf);
        float2 A  = make_float2(ca, sa);
        float2 Bb = make_float2(cb, sb);
        float2 F  = make_float2(cf, sf);
        float2 Tm  = make_float2(0.5f * (ct - 1.0f), 0.5f * st);  // (T-1)/2
        float2 Tp  = make_float2(0.5f * (ct + 1.0f), 0.5f * st);  // (T+1)/2
        float2 iTp = make_float2(-Tp.y, Tp.x);                    // i*(T+1)/2
        Mg[p * 4 + 0] = cmulh(cmulh(F, Tm), A);
        Mg[p * 4 + 1] = cmulh(cmulh(F, iTp), Bb);
        Mg[p * 4 + 2] = cmulh(iTp, A);
        Mg[p * 4 + 3] = cmulh(make_float2(-Tm.x, -Tm.y), Bb);
    }
}

// One block per batch row; thread T holds 16 complex elements.
// Mapping A: i = (s>>2)<<10 | T<<2 | (s&3)            -> slot bits {0,1,10,11}
// Mapping B: i = T[7:6]<<10 | T[5:2]<<6 | s<<2 | T[1:0] -> slot bits {2..5}
// Mapping C: i = T[7:6]<<10 | s<<6 | T[5:0]           -> slot bits {6..9}
// LDS swizzle swz(i) = i ^ ((i>>4)&0xF): preserves bits [11:4]; every b64
// access pattern sits at the 4-access/bank floor (verified 0 conflicts in R2).
// A->B crosses waves (bits 10,11 in slots)  -> 1 __syncthreads pair.
// B->C keeps i[11:10] == T[7:6] (the wave id) -> WAVE-LOCAL, no barrier:
// each thread writes exactly the addresses it read (B), then reads only its
// own wave's region (C); same-wave DS ops complete in order.
__global__ __launch_bounds__(256) void sq_layer(const float* __restrict__ x,
                                                const float2* __restrict__ Mgf,
                                                float* __restrict__ out) {
    __shared__ f2 lds[NN];  // 32 KB
    const int T = threadIdx.x;
    const size_t rowoff = (size_t)blockIdx.x * (2 * NN);
    const f2* Mg = (const f2*)Mgf;

    f2 v[16];
    // ---- load (mapping A), coalesced float4 ----
    #pragma unroll
    for (int rhi = 0; rhi < 4; ++rhi) {
        int base = (rhi << 10) + (T << 2);
        float4 re4 = *reinterpret_cast<const float4*>(x + rowoff + base);
        float4 im4 = *reinterpret_cast<const float4*>(x + rowoff + NN + base);
        v[rhi * 4 + 0] = f2{re4.x, im4.x};
        v[rhi * 4 + 1] = f2{re4.y, im4.y};
        v[rhi * 4 + 2] = f2{re4.z, im4.z};
        v[rhi * 4 + 3] = f2{re4.w, im4.w};
    }

    // ---- phase 1: bits 0 (D=1), 1 (D=2), 10 (D=4), 11 (D=8) ----
    stagepk<1>(v, Mg[0],  Mg[1],  Mg[2],  Mg[3]);
    stagepk<2>(v, Mg[4],  Mg[5],  Mg[6],  Mg[7]);
    stagepk<4>(v, Mg[40], Mg[41], Mg[42], Mg[43]);
    stagepk<8>(v, Mg[44], Mg[45], Mg[46], Mg[47]);

    // ---- transpose A -> B (cross-wave; one barrier) ----
    // swz(A(s)): mask = (i>>4)&0xF = (T>>2)&0xF, constant per thread:
    // addr = ((s>>2)<<10) | (baseA ^ (s&3)),  baseA = (T<<2) ^ ((T>>2)&0xF)
    {
        const int baseA = (T << 2) ^ ((T >> 2) & 0xF);
        #pragma unroll
        for (int s = 0; s < 16; ++s)
            lds[((s >> 2) << 10) | (baseA ^ (s & 3))] = v[s];
    }
    __syncthreads();
    // read B: i = bB | s<<2, mask = (T[3:2]<<2) | (s>>2)
    // addr = cB ^ ((s<<2) ^ (s>>2)),  cB = bB ^ ((T>>2)&3)<<2
    const int bB = ((T >> 6) << 10) | (((T >> 2) & 0xF) << 6) | (T & 3);
    const int cB = bB ^ ((((T >> 2) & 3)) << 2);
    #pragma unroll
    for (int s = 0; s < 16; ++s) v[s] = lds[cB ^ ((s << 2) ^ (s >> 2))];

    // ---- phase 2: bits 2,3,4,5 ----
    stagepk<1>(v, Mg[8],  Mg[9],  Mg[10], Mg[11]);
    stagepk<2>(v, Mg[12], Mg[13], Mg[14], Mg[15]);
    stagepk<4>(v, Mg[16], Mg[17], Mg[18], Mg[19]);
    stagepk<8>(v, Mg[20], Mg[21], Mg[22], Mg[23]);

    // ---- transpose B -> C (wave-local; NO barrier) ----
    #pragma unroll
    for (int s = 0; s < 16; ++s) lds[cB ^ ((s << 2) ^ (s >> 2))] = v[s];
    // read C: i = bC | s<<6, mask = ((s&3)<<2) | T[5:4]
    // addr = (cC ^ ((s&3)<<2)) | (s<<6),  cC = bC ^ ((T>>4)&3)
    const int bC = ((T >> 6) << 10) | (T & 63);
    const int cC = bC ^ ((T >> 4) & 3);
    #pragma unroll
    for (int s = 0; s < 16; ++s) v[s] = lds[(cC ^ ((s & 3) << 2)) | (s << 6)];

    // ---- phase 3: bits 6,7,8,9 ----
    stagepk<1>(v, Mg[24], Mg[25], Mg[26], Mg[27]);
    stagepk<2>(v, Mg[28], Mg[29], Mg[30], Mg[31]);
    stagepk<4>(v, Mg[32], Mg[33], Mg[34], Mg[35]);
    stagepk<8>(v, Mg[36], Mg[37], Mg[38], Mg[39]);

    // ---- store (mapping C): per slot, 64 consecutive dwords per wave ----
    #pragma unroll
    for (int s = 0; s < 16; ++s) {
        int i = bC | (s << 6);
        out[rowoff + i]      = v[s].x;
        out[rowoff + NN + i] = v[s].y;
    }
}

extern "C" void kernel_launch(void* const* d_in, const int* in_sizes, int n_in,
                              void* d_out, int out_size, void* d_ws, size_t ws_size,
                              hipStream_t stream) {
    const float* x      = (const float*)d_in[0];
    const float* alphas = (const float*)d_in[1];
    const float* betas  = (const float*)d_in[2];
    const float* thetas = (const float*)d_in[3];
    const float* phis   = (const float*)d_in[4];
    float* out = (float*)d_out;
    float2* Mg = (float2*)d_ws;   // 48 float2 = 384 B

    const int B = in_sizes[0] / (2 * NN);  // 2048

    hipLaunchKernelGGL(setup_mats, dim3(1), dim3(64), 0, stream,
                       alphas, betas, thetas, phis, Mg);
    hipLaunchKernelGGL(sq_layer, dim3(B), dim3(256), 0, stream,
                       x, (const float2*)Mg, out);
}

// Round 5
// 32.683 us; speedup vs baseline: 1.2914x; 1.0317x over previous
//
#include <hip/hip_runtime.h>
#include <math.h>

#define NQ 12
#define NN 4096   // 2^12

typedef float f2 __attribute__((ext_vector_type(2)));  // (re, im) in a VGPR pair

__device__ __forceinline__ float2 cmulh(float2 a, float2 b) {
    return make_float2(a.x * b.x - a.y * b.y, a.x * b.y + a.y * b.x);
}

// ---- packed complex arithmetic: 2 x v_pk_fma_f32 per complex MAC ----
// m = [mr, mi] (SGPR pair, uniform), b = [br, bi], acc = [ar, ai].
__device__ __forceinline__ void cmac_pk(f2& acc, f2 m, f2 b) {
    asm("v_pk_fma_f32 %0, %1, %2, %0 op_sel:[0,0,0] op_sel_hi:[0,1,1]\n\t"
        "v_pk_fma_f32 %0, %1, %2, %0 op_sel:[1,1,0] op_sel_hi:[1,0,1] neg_lo:[1,0,0]"
        : "+v"(acc) : "s"(m), "v"(b));
}
__device__ __forceinline__ void cmul_pk(f2& r, f2 m, f2 b) {
    asm("v_pk_mul_f32 %0, %1, %2 op_sel:[0,0] op_sel_hi:[0,1]\n\t"
        "v_pk_fma_f32 %0, %1, %2, %0 op_sel:[1,1,0] op_sel_hi:[1,0,1] neg_lo:[1,0,0]"
        : "=&v"(r) : "s"(m), "v"(b));
}

// Radix-2 butterfly on slot bit log2(D) over 8 slots.
template<int D>
__device__ __forceinline__ void stagepk8(f2 (&v)[8], f2 m00, f2 m01, f2 m10, f2 m11) {
    #pragma unroll
    for (int s = 0; s < 8; ++s) {
        if (s & D) continue;
        f2 va = v[s], vb = v[s | D];
        f2 r0, r1;
        cmul_pk(r0, m00, va); cmac_pk(r0, m01, vb);
        cmul_pk(r1, m10, va); cmac_pk(r1, m11, vb);
        v[s] = r0; v[s | D] = r1;
    }
}

// d_ws: Mg[p*4 + {m00,m01,m10,m11}] for bit position p = 0..11.
// M_p = diag(e^{i phi},1) * u * diag(e^{i theta},1) * u * diag(e^{i a}, e^{i b}),
// u = (1/sqrt2)[[1,i],[i,1]], parameter index q = 11-p.
__global__ void setup_mats(const float* __restrict__ alphas,
                           const float* __restrict__ betas,
                           const float* __restrict__ thetas,
                           const float* __restrict__ phis,
                           float2* __restrict__ Mg) {
    int t = threadIdx.x;
    if (t < NQ) {
        int p = t, q = NQ - 1 - p;
        float sa, ca, sb, cb, st, ct, sf, cf;
        sincosf(alphas[q], &sa, &ca);
        sincosf(betas[q],  &sb, &cb);
        sincosf(thetas[q], &st, &ct);
        sincosf(phis[q],   &sf, &cf);
        float2 A  = make_float2(ca, sa);
        float2 Bb = make_float2(cb, sb);
        float2 F  = make_float2(cf, sf);
        float2 Tm  = make_float2(0.5f * (ct - 1.0f), 0.5f * st);  // (T-1)/2
        float2 Tp  = make_float2(0.5f * (ct + 1.0f), 0.5f * st);  // (T+1)/2
        float2 iTp = make_float2(-Tp.y, Tp.x);                    // i*(T+1)/2
        Mg[p * 4 + 0] = cmulh(cmulh(F, Tm), A);
        Mg[p * 4 + 1] = cmulh(cmulh(F, iTp), Bb);
        Mg[p * 4 + 2] = cmulh(iTp, A);
        Mg[p * 4 + 3] = cmulh(make_float2(-Tm.x, -Tm.y), Bb);
    }
}

// 512 threads/block, one batch row per block, 8 complex elements/thread.
// Mappings (T = thread 9 bits, s = slot 3 bits):
//   A: i = T<<3 | s                         -> slot bits {0,1,2}
//   B: i = (T>>3)<<6 | s<<3 | (T&7)         -> slot bits {3,4,5}
//   C: i = (T>>6)<<9 | s<<6 | (T&63)        -> slot bits {6,7,8}
//   D: i = s<<9 | T                         -> slot bits {9,10,11}
// LDS layout: idx(i) = i + (i>>3) (stride-9/8 padding; 4608 f2 = 36 KB).
// A, B, C all have i[11:9] == T[8:6] (the wave id) -> transposes A->B, B->C
// and the C-side write of C->D touch ONLY the wave's own 576-f2 region;
// same-wave DS ops complete in order, so no barrier (R4-verified).
// Only the D-read crosses waves -> exactly ONE __syncthreads().
__global__ __launch_bounds__(512, 8) void sq_layer(const float* __restrict__ x,
                                                   const float2* __restrict__ Mgf,
                                                   float* __restrict__ out) {
    __shared__ f2 lds[4608];  // 36 KB
    const int T = threadIdx.x;
    const size_t rowoff = (size_t)blockIdx.x * (2 * NN);
    const f2* Mg = (const f2*)Mgf;

    f2 v[8];
    // ---- load (mapping A): 4 coalesced float4 ----
    {
        const float* px = x + rowoff + (T << 3);
        float4 ra = *reinterpret_cast<const float4*>(px);
        float4 rb = *reinterpret_cast<const float4*>(px + 4);
        float4 ia = *reinterpret_cast<const float4*>(px + NN);
        float4 ib = *reinterpret_cast<const float4*>(px + NN + 4);
        v[0] = f2{ra.x, ia.x}; v[1] = f2{ra.y, ia.y};
        v[2] = f2{ra.z, ia.z}; v[3] = f2{ra.w, ia.w};
        v[4] = f2{rb.x, ib.x}; v[5] = f2{rb.y, ib.y};
        v[6] = f2{rb.z, ib.z}; v[7] = f2{rb.w, ib.w};
    }

    // ---- phase 1: bits 0,1,2 ----
    stagepk8<1>(v, Mg[0],  Mg[1],  Mg[2],  Mg[3]);
    stagepk8<2>(v, Mg[4],  Mg[5],  Mg[6],  Mg[7]);
    stagepk8<4>(v, Mg[8],  Mg[9],  Mg[10], Mg[11]);

    // ---- transpose A -> B (wave-region-local, no barrier) ----
    // write A: idx(8T+s) = 9T + s ; read B: idx = 72*(T>>3) + (T&7) + 9s
    {
        f2* wp = lds + 9 * T;
        #pragma unroll
        for (int s = 0; s < 8; ++s) wp[s] = v[s];
    }
    {
        const f2* rp = lds + 72 * (T >> 3) + (T & 7);
        #pragma unroll
        for (int s = 0; s < 8; ++s) v[s] = rp[9 * s];
    }

    // ---- phase 2: bits 3,4,5 ----
    stagepk8<1>(v, Mg[12], Mg[13], Mg[14], Mg[15]);
    stagepk8<2>(v, Mg[16], Mg[17], Mg[18], Mg[19]);
    stagepk8<4>(v, Mg[20], Mg[21], Mg[22], Mg[23]);

    // ---- transpose B -> C (wave-region-local, no barrier) ----
    // write B (same addrs as B-read); read C: idx = 576*(T>>6) + (T&63) + ((T&63)>>3) + 72s
    {
        f2* wp = lds + 72 * (T >> 3) + (T & 7);
        #pragma unroll
        for (int s = 0; s < 8; ++s) wp[9 * s] = v[s];
    }
    {
        const f2* rp = lds + 576 * (T >> 6) + (T & 63) + ((T & 63) >> 3);
        #pragma unroll
        for (int s = 0; s < 8; ++s) v[s] = rp[72 * s];
    }

    // ---- phase 3: bits 6,7,8 ----
    stagepk8<1>(v, Mg[24], Mg[25], Mg[26], Mg[27]);
    stagepk8<2>(v, Mg[28], Mg[29], Mg[30], Mg[31]);
    stagepk8<4>(v, Mg[32], Mg[33], Mg[34], Mg[35]);

    // ---- transpose C -> D: write C (own region), BARRIER, read D (cross-wave) ----
    {
        f2* wp = lds + 576 * (T >> 6) + (T & 63) + ((T & 63) >> 3);
        #pragma unroll
        for (int s = 0; s < 8; ++s) wp[72 * s] = v[s];
    }
    __syncthreads();
    {
        const f2* rp = lds + T + (T >> 3);   // idx(s<<9 | T) = 576s + T + (T>>3)
        #pragma unroll
        for (int s = 0; s < 8; ++s) v[s] = rp[576 * s];
    }

    // ---- phase 4: bits 9,10,11 ----
    stagepk8<1>(v, Mg[36], Mg[37], Mg[38], Mg[39]);
    stagepk8<2>(v, Mg[40], Mg[41], Mg[42], Mg[43]);
    stagepk8<4>(v, Mg[44], Mg[45], Mg[46], Mg[47]);

    // ---- store (mapping D): i = s<<9 | T, wave-contiguous dwords ----
    #pragma unroll
    for (int s = 0; s < 8; ++s) {
        int i = (s << 9) | T;
        out[rowoff + i]      = v[s].x;
        out[rowoff + NN + i] = v[s].y;
    }
}

extern "C" void kernel_launch(void* const* d_in, const int* in_sizes, int n_in,
                              void* d_out, int out_size, void* d_ws, size_t ws_size,
                              hipStream_t stream) {
    const float* x      = (const float*)d_in[0];
    const float* alphas = (const float*)d_in[1];
    const float* betas  = (const float*)d_in[2];
    const float* thetas = (const float*)d_in[3];
    const float* phis   = (const float*)d_in[4];
    float* out = (float*)d_out;
    float2* Mg = (float2*)d_ws;   // 48 float2 = 384 B

    const int B = in_sizes[0] / (2 * NN);  // 2048

    hipLaunchKernelGGL(setup_mats, dim3(1), dim3(64), 0, stream,
                       alphas, betas, thetas, phis, Mg);
    hipLaunchKernelGGL(sq_layer, dim3(B), dim3(512), 0, stream,
                       x, (const float2*)Mg, out);
}

// Round 6
// 31.525 us; speedup vs baseline: 1.3388x; 1.0367x over previous
//
#include <hip/hip_runtime.h>
#include <math.h>

#define NQ 12
#define NN 4096   // 2^12

typedef float f2 __attribute__((ext_vector_type(2)));  // (re, im) in a VGPR pair

__device__ __forceinline__ float2 cmulh(float2 a, float2 b) {
    return make_float2(a.x * b.x - a.y * b.y, a.x * b.y + a.y * b.x);
}

// ---- packed complex arithmetic: 2 x v_pk_fma_f32 per complex MAC ----
// m = [mr, mi] (SGPR pair, uniform), b = [br, bi], acc = [ar, ai].
__device__ __forceinline__ void cmac_pk(f2& acc, f2 m, f2 b) {
    asm("v_pk_fma_f32 %0, %1, %2, %0 op_sel:[0,0,0] op_sel_hi:[0,1,1]\n\t"
        "v_pk_fma_f32 %0, %1, %2, %0 op_sel:[1,1,0] op_sel_hi:[1,0,1] neg_lo:[1,0,0]"
        : "+v"(acc) : "s"(m), "v"(b));
}
__device__ __forceinline__ void cmul_pk(f2& r, f2 m, f2 b) {
    asm("v_pk_mul_f32 %0, %1, %2 op_sel:[0,0] op_sel_hi:[0,1]\n\t"
        "v_pk_fma_f32 %0, %1, %2, %0 op_sel:[1,1,0] op_sel_hi:[1,0,1] neg_lo:[1,0,0]"
        : "=&v"(r) : "s"(m), "v"(b));
}

// Radix-2 butterfly on slot bit log2(D) over 8 slots.
template<int D>
__device__ __forceinline__ void stagepk8(f2 (&v)[8], f2 m00, f2 m01, f2 m10, f2 m11) {
    #pragma unroll
    for (int s = 0; s < 8; ++s) {
        if (s & D) continue;
        f2 va = v[s], vb = v[s | D];
        f2 r0, r1;
        cmul_pk(r0, m00, va); cmac_pk(r0, m01, vb);
        cmul_pk(r1, m10, va); cmac_pk(r1, m11, vb);
        v[s] = r0; v[s | D] = r1;
    }
}

// d_ws: Mg[p*4 + {m00,m01,m10,m11}] for bit position p = 0..11.
// M_p = diag(e^{i phi},1) * u * diag(e^{i theta},1) * u * diag(e^{i a}, e^{i b}),
// u = (1/sqrt2)[[1,i],[i,1]], parameter index q = 11-p.
__global__ void setup_mats(const float* __restrict__ alphas,
                           const float* __restrict__ betas,
                           const float* __restrict__ thetas,
                           const float* __restrict__ phis,
                           float2* __restrict__ Mg) {
    int t = threadIdx.x;
    if (t < NQ) {
        int p = t, q = NQ - 1 - p;
        float sa, ca, sb, cb, st, ct, sf, cf;
        sincosf(alphas[q], &sa, &ca);
        sincosf(betas[q],  &sb, &cb);
        sincosf(thetas[q], &st, &ct);
        sincosf(phis[q],   &sf, &cf);
        float2 A  = make_float2(ca, sa);
        float2 Bb = make_float2(cb, sb);
        float2 F  = make_float2(cf, sf);
        float2 Tm  = make_float2(0.5f * (ct - 1.0f), 0.5f * st);  // (T-1)/2
        float2 Tp  = make_float2(0.5f * (ct + 1.0f), 0.5f * st);  // (T+1)/2
        float2 iTp = make_float2(-Tp.y, Tp.x);                    // i*(T+1)/2
        Mg[p * 4 + 0] = cmulh(cmulh(F, Tm), A);
        Mg[p * 4 + 1] = cmulh(cmulh(F, iTp), Bb);
        Mg[p * 4 + 2] = cmulh(iTp, A);
        Mg[p * 4 + 3] = cmulh(make_float2(-Tm.x, -Tm.y), Bb);
    }
}

// 512 threads/block, TWO batch rows per block (grid = B/2 = 1024, fully
// resident at 4 blocks/CU), 8 complex elements/thread.
// Mappings (T = thread 9 bits, s = slot 3 bits):
//   A: i = T<<3 | s                         -> slot bits {0,1,2}
//   B: i = (T>>3)<<6 | s<<3 | (T&7)         -> slot bits {3,4,5}
//   C: i = (T>>6)<<9 | s<<6 | (T&63)        -> slot bits {6,7,8}
//   D: i = s<<9 | T                         -> slot bits {9,10,11}
// LDS layout: idx(i) = i + (i>>3) (stride-9/8 padding; 4608 f2 = 36 KB).
// A, B, C all have i[11:9] == T[8:6] (the wave id) -> transposes A->B, B->C
// and the C-side write of C->D are wave-region-local (in-order DS pipe, no
// barrier). Only the D-read crosses waves -> barrier before it; and a second
// barrier after it (row 0 only) so row 1's T1 writes can't race other waves'
// D-reads. Next-row global loads are issued at the top of the current row's
// compute so HBM latency hides under ~1.5 us of VALU/DS work. Stores are
// non-temporal: the output is never re-read, and bypassing L2/L3 allocation
// keeps the input x resident in the 256 MiB L3 across graph replays.
__global__ __launch_bounds__(512, 8) void sq_layer(const float* __restrict__ x,
                                                   const float2* __restrict__ Mgf,
                                                   float* __restrict__ out) {
    __shared__ f2 lds[4608];  // 36 KB
    const int T = threadIdx.x;
    const f2* Mg = (const f2*)Mgf;
    const size_t row0 = (size_t)blockIdx.x * 2;

    const float* px = x + row0 * (2 * NN) + (T << 3);
    float4 ra = *reinterpret_cast<const float4*>(px);
    float4 rb = *reinterpret_cast<const float4*>(px + 4);
    float4 ia = *reinterpret_cast<const float4*>(px + NN);
    float4 ib = *reinterpret_cast<const float4*>(px + NN + 4);

    #pragma unroll
    for (int r = 0; r < 2; ++r) {
        f2 v[8];
        v[0] = f2{ra.x, ia.x}; v[1] = f2{ra.y, ia.y};
        v[2] = f2{ra.z, ia.z}; v[3] = f2{ra.w, ia.w};
        v[4] = f2{rb.x, ib.x}; v[5] = f2{rb.y, ib.y};
        v[6] = f2{rb.z, ib.z}; v[7] = f2{rb.w, ib.w};

        if (r == 0) {  // prefetch row 1; completes under row-0 compute
            const float* pn = px + 2 * NN;
            ra = *reinterpret_cast<const float4*>(pn);
            rb = *reinterpret_cast<const float4*>(pn + 4);
            ia = *reinterpret_cast<const float4*>(pn + NN);
            ib = *reinterpret_cast<const float4*>(pn + NN + 4);
        }

        // ---- phase 1: bits 0,1,2 ----
        stagepk8<1>(v, Mg[0],  Mg[1],  Mg[2],  Mg[3]);
        stagepk8<2>(v, Mg[4],  Mg[5],  Mg[6],  Mg[7]);
        stagepk8<4>(v, Mg[8],  Mg[9],  Mg[10], Mg[11]);

        // ---- transpose A -> B (wave-region-local, no barrier) ----
        {
            f2* wp = lds + 9 * T;
            #pragma unroll
            for (int s = 0; s < 8; ++s) wp[s] = v[s];
        }
        {
            const f2* rp = lds + 72 * (T >> 3) + (T & 7);
            #pragma unroll
            for (int s = 0; s < 8; ++s) v[s] = rp[9 * s];
        }

        // ---- phase 2: bits 3,4,5 ----
        stagepk8<1>(v, Mg[12], Mg[13], Mg[14], Mg[15]);
        stagepk8<2>(v, Mg[16], Mg[17], Mg[18], Mg[19]);
        stagepk8<4>(v, Mg[20], Mg[21], Mg[22], Mg[23]);

        // ---- transpose B -> C (wave-region-local, no barrier) ----
        {
            f2* wp = lds + 72 * (T >> 3) + (T & 7);
            #pragma unroll
            for (int s = 0; s < 8; ++s) wp[9 * s] = v[s];
        }
        {
            const f2* rp = lds + 576 * (T >> 6) + (T & 63) + ((T & 63) >> 3);
            #pragma unroll
            for (int s = 0; s < 8; ++s) v[s] = rp[72 * s];
        }

        // ---- phase 3: bits 6,7,8 ----
        stagepk8<1>(v, Mg[24], Mg[25], Mg[26], Mg[27]);
        stagepk8<2>(v, Mg[28], Mg[29], Mg[30], Mg[31]);
        stagepk8<4>(v, Mg[32], Mg[33], Mg[34], Mg[35]);

        // ---- transpose C -> D: write C (own region), BARRIER, read D ----
        {
            f2* wp = lds + 576 * (T >> 6) + (T & 63) + ((T & 63) >> 3);
            #pragma unroll
            for (int s = 0; s < 8; ++s) wp[72 * s] = v[s];
        }
        __syncthreads();
        {
            const f2* rp = lds + T + (T >> 3);   // idx(s<<9 | T) = 576s + T + (T>>3)
            #pragma unroll
            for (int s = 0; s < 8; ++s) v[s] = rp[576 * s];
        }
        if (r == 0) __syncthreads();  // D-reads done before row 1's T1 writes

        // ---- phase 4: bits 9,10,11 ----
        stagepk8<1>(v, Mg[36], Mg[37], Mg[38], Mg[39]);
        stagepk8<2>(v, Mg[40], Mg[41], Mg[42], Mg[43]);
        stagepk8<4>(v, Mg[44], Mg[45], Mg[46], Mg[47]);

        // ---- store (mapping D): i = s<<9 | T, wave-contiguous, non-temporal ----
        {
            float* po = out + (row0 + r) * (2 * NN);
            #pragma unroll
            for (int s = 0; s < 8; ++s) {
                int i = (s << 9) | T;
                __builtin_nontemporal_store(v[s].x, po + i);
                __builtin_nontemporal_store(v[s].y, po + NN + i);
            }
        }
    }
}

extern "C" void kernel_launch(void* const* d_in, const int* in_sizes, int n_in,
                              void* d_out, int out_size, void* d_ws, size_t ws_size,
                              hipStream_t stream) {
    const float* x      = (const float*)d_in[0];
    const float* alphas = (const float*)d_in[1];
    const float* betas  = (const float*)d_in[2];
    const float* thetas = (const float*)d_in[3];
    const float* phis   = (const float*)d_in[4];
    float* out = (float*)d_out;
    float2* Mg = (float2*)d_ws;   // 48 float2 = 384 B

    const int B = in_sizes[0] / (2 * NN);  // 2048

    hipLaunchKernelGGL(setup_mats, dim3(1), dim3(64), 0, stream,
                       alphas, betas, thetas, phis, Mg);
    hipLaunchKernelGGL(sq_layer, dim3(B / 2), dim3(512), 0, stream,
                       x, (const float2*)Mg, out);
}